// Round 15
// baseline (27102.679 us; speedup 1.0000x reference)
//
#include <hip/hip_runtime.h>
#include <hip/hip_cooperative_groups.h>
#include <hip/hip_bf16.h>
#include <hip/hip_fp16.h>
#include <math.h>

namespace cg = cooperative_groups;

// Problem sizes
#define BB 256
#define TT 64
#define HH 512
#define SS 256
#define KKC 1024

// ws float offsets — 788,480 floats = 3.15 MB
#define OFF_XE 0
#define OFF_XS (OFF_XE + BB*HH)
#define OFF_HA (OFF_XS + BB*HH)
#define OFF_HB (OFF_HA + BB*HH)
#define OFF_C  (OFF_HB + BB*HH)
#define OFF_XO (OFF_C  + BB*HH)
#define OFF_SLOT (OFF_XO + BB*HH)   // 1024 u64 argmax slots

__device__ __forceinline__ unsigned encf(float f) {
  unsigned u = __float_as_uint(f);
  return (u & 0x80000000u) ? ~u : (u | 0x80000000u);
}

__device__ __forceinline__ unsigned long long shfl_xor_u64(unsigned long long v, int m) {
  unsigned lo = (unsigned)v, hi = (unsigned)(v >> 32);
  lo = __shfl_xor(lo, m, 64);
  hi = __shfl_xor(hi, m, 64);
  return ((unsigned long long)hi << 32) | lo;
}

__device__ __forceinline__ int decode_mask(const int* p) {
  if (p == nullptr) return 32;
  unsigned w0 = (unsigned)p[0];
  if (w0 >= 1u && w0 <= 63u) return (int)w0;
  { float f = __uint_as_float(w0);
    if (f >= 1.f && f <= 63.f && f == floorf(f)) return (int)f; }
  if (w0 == 0u) {
    double dv = __hiloint2double(p[1], 0);
    if (dv >= 1.0 && dv <= 63.0 && dv == floor(dv)) return (int)dv;
    return 32;
  }
  if (w0 <= 0xFFFFu) {
    float fb = __uint_as_float(w0 << 16);
    if (fb >= 1.f && fb <= 63.f && fb == floorf(fb)) return (int)fb;
    __half_raw hr; hr.x = (unsigned short)w0;
    float fh = __half2float(__half(hr));
    if (fh >= 1.f && fh <= 63.f && fh == floorf(fh)) return (int)fh;
  }
  return 32;
}

struct KParams {
  const float *obs, *social;
  const int   *maskp;
  const float *cx, *cy, *cw, *ch;
  const float *W_rb1, *b_rb1, *W_rb2, *b_rb2, *W_rbs, *b_rbs;
  const float *W_emb, *b_emb;
  const float *W_ih, *b_ih, *W_hh, *b_hh;
  const float *W_fx, *b_fx, *W_fy, *b_fy, *W_fw, *b_fw, *W_fh, *b_fh;
  const float *h0, *c0;
  float *ws, *out;
};

// LDS union kept <= 28 KB so the cooperative occupancy check passes easily.
union SMem {
  struct { float x[8][4]; float xr[64][12]; float w[64][68]; } xe;     // ~20.6 KB
  struct { float A[64][12]; float w[64][68]; } xs;                     // ~20.4 KB
  struct { float A[32][20]; float w[32][132]; float gt[16][132]; } g;  // ~27.9 KB
  struct { float A[32][20]; float w[32][132]; } h;                     // ~19.4 KB
};

// =================== cooperative single-kernel path ===================
// 256 blocks (1/CU) x 512 threads (8 waves/CU)
__global__ __launch_bounds__(512, 2) void k_all(KParams P)
{
  cg::grid_group gridg = cg::this_grid();
  __shared__ SMem sm;
  const int bid = blockIdx.x, tid = threadIdx.x;
  float* ws = P.ws;
  float* out = P.out;
  unsigned long long* slots = (unsigned long long*)(ws + OFF_SLOT);

  // init: h,c and output edges
  {
    int i = bid*512 + tid;          // exactly BB*HH
    ws[OFF_HA + i] = P.h0[i];
    ws[OFF_C  + i] = P.c0[i];
    if (i < BB*4) {
      int b = i >> 2, d = i & 3;
      out[(b*TT + 0)*4 + d]  = P.obs[(b*TT + 0)*4 + d];
      out[(b*TT + 63)*4 + d] = P.obs[(b*TT + 63)*4 + d];
    }
  }
  __threadfence();
  gridg.sync();

  for (int t = 0; t < 63; t++) {
    const float* h_cur = ws + ((t & 1) ? OFF_HB : OFF_HA);
    float*       h_nxt = ws + ((t & 1) ? OFF_HA : OFF_HB);

    // ======== phase 1: sample + residual block -> xe ========
    // 256 = 32 rowg x 8 colg ; tile 8 rows x 64 cols, k=512 in 8 tiles of 64
    {
      int rowg = bid >> 3, colg = bid & 7;
      int r0 = rowg*8, c0 = colg*64;
      if (tid < 32) {
        int r = tid >> 2, hd = tid & 3, b = r0 + r;
        int mi = decode_mask(P.maskp);
        float v;
        if (t == 0 || t < mi) {
          v = P.obs[(b*TT + t)*4 + hd];
        } else {
          unsigned long long s = slots[b*4 + hd];
          unsigned int kidx = 0xFFFFFFFFu - (unsigned int)(s & 0xFFFFFFFFull);
          const float* cen = hd==0 ? P.cx : (hd==1 ? P.cy : (hd==2 ? P.cw : P.ch));
          v = cen[kidx & (KKC-1)];
        }
        sm.xe.x[r][hd] = v;
        if (t >= 1 && colg == 0) out[(b*TT + t)*4 + hd] = v;
      }
      __syncthreads();
      int c = tid & 63, rg = tid >> 6;   // 64 cols x 8 rows
      int col = c0 + c;
      float4 wsd = *(const float4*)&P.W_rbs[col*4];
      float acc = P.b_rb2[col] + P.b_rbs[col]
                + sm.xe.x[rg][0]*wsd.x + sm.xe.x[rg][1]*wsd.y
                + sm.xe.x[rg][2]*wsd.z + sm.xe.x[rg][3]*wsd.w;
      for (int kt = 0; kt < 8; kt++) {
        __syncthreads();
        { // fc1 on the fly for this k-tile: 64 j x 8 r
          int jl = tid >> 3, r = tid & 7;
          int j = kt*64 + jl;
          float4 w = *(const float4*)&P.W_rb1[j*4];
          float a = P.b_rb1[j] + sm.xe.x[r][0]*w.x + sm.xe.x[r][1]*w.y
                               + sm.xe.x[r][2]*w.z + sm.xe.x[r][3]*w.w;
          sm.xe.xr[jl][r] = fmaxf(a, 0.f);
        }
        for (int p = 0; p < 2; p++) { // stage W: 64k x 64c
          int idx = tid + p*512;
          int wc = idx >> 4, kq = idx & 15;
          float4 v = *(const float4*)&P.W_rb2[(c0+wc)*HH + kt*64 + kq*4];
          sm.xe.w[kq*4+0][wc] = v.x; sm.xe.w[kq*4+1][wc] = v.y;
          sm.xe.w[kq*4+2][wc] = v.z; sm.xe.w[kq*4+3][wc] = v.w;
        }
        __syncthreads();
        #pragma unroll 8
        for (int kk = 0; kk < 64; kk++)
          acc = fmaf(sm.xe.xr[kk][rg], sm.xe.w[kk][c], acc);
      }
      ws[OFF_XE + (r0+rg)*HH + col] = fmaxf(acc, 0.f);
    }
    __threadfence();
    gridg.sync();

    // ======== phase 2: embedding -> xs ========
    // 256 = 32 rowg x 8 colg ; tile 8 x 64, k=768 in 12 tiles of 64
    {
      int rowg = bid >> 3, colg = bid & 7;
      int r0 = rowg*8, c0 = colg*64;
      int c = tid & 63, rg = tid >> 6;
      int col = c0 + c;
      float acc = P.b_emb[col];
      const float* XE = ws + OFF_XE;
      for (int kt = 0; kt < 12; kt++) {
        int k0 = kt*64;
        __syncthreads();
        if (tid < 128) { // stage A: 64k x 8r
          int r = tid & 7, q = tid >> 3;
          const float* src = (kt < 8) ? &XE[(r0+r)*HH + k0 + q*4]
                                      : &P.social[((size_t)(r0+r)*TT + t)*SS + (k0 - HH) + q*4];
          float4 v = *(const float4*)src;
          sm.xs.A[q*4+0][r] = v.x; sm.xs.A[q*4+1][r] = v.y;
          sm.xs.A[q*4+2][r] = v.z; sm.xs.A[q*4+3][r] = v.w;
        }
        for (int p = 0; p < 2; p++) { // stage W: 64k x 64c
          int idx = tid + p*512;
          int wc = idx >> 4, kq = idx & 15;
          float4 v = *(const float4*)&P.W_emb[(c0+wc)*768 + k0 + kq*4];
          sm.xs.w[kq*4+0][wc] = v.x; sm.xs.w[kq*4+1][wc] = v.y;
          sm.xs.w[kq*4+2][wc] = v.z; sm.xs.w[kq*4+3][wc] = v.w;
        }
        __syncthreads();
        #pragma unroll 8
        for (int kk = 0; kk < 64; kk++)
          acc = fmaf(sm.xs.A[kk][rg], sm.xs.w[kk][c], acc);
      }
      ws[OFF_XS + (r0+rg)*HH + col] = fmaxf(acc, 0.f);
    }
    __threadfence();
    gridg.sync();

    // ======== phase 3: LSTM gates + cell update ========
    // 256 = 16 rowg x 16 colg ; tile 16 rows x 128 gate-cols (32 h), k=1024 in 32 tiles of 32
    {
      int rowg = bid >> 4, colg = bid & 15;
      int r0 = rowg*16;
      int tx = tid & 127, rg4 = tid >> 7;   // 128 cols ; 4 row-groups x 4 rows
      const float* XS = ws + OFF_XS;
      int wrow = (tx & 3)*HH + colg*32 + (tx >> 2);
      float bias = P.b_ih[wrow] + P.b_hh[wrow];
      float acc[4];
      #pragma unroll
      for (int i = 0; i < 4; i++) acc[i] = bias;
      for (int kt = 0; kt < 32; kt++) {
        int k0 = kt*32;
        __syncthreads();
        if (tid < 128) { // stage A: 32k x 16r
          int r = tid & 15, q = tid >> 4;
          const float* src = (kt < 16) ? &XS[(r0+r)*HH + k0 + q*4]
                                       : &h_cur[(r0+r)*HH + (k0 - HH) + q*4];
          float4 v = *(const float4*)src;
          sm.g.A[q*4+0][r] = v.x; sm.g.A[q*4+1][r] = v.y;
          sm.g.A[q*4+2][r] = v.z; sm.g.A[q*4+3][r] = v.w;
        }
        for (int p = 0; p < 2; p++) { // stage W: 32k x 128c
          int idx = tid + p*512;
          int wc = idx >> 3, kq = idx & 7;
          int wr = (wc & 3)*HH + colg*32 + (wc >> 2);
          const float* wsrc = (kt < 16) ? &P.W_ih[wr*HH + k0 + kq*4]
                                        : &P.W_hh[wr*HH + (k0 - HH) + kq*4];
          float4 v = *(const float4*)wsrc;
          sm.g.w[kq*4+0][wc] = v.x; sm.g.w[kq*4+1][wc] = v.y;
          sm.g.w[kq*4+2][wc] = v.z; sm.g.w[kq*4+3][wc] = v.w;
        }
        __syncthreads();
        #pragma unroll 4
        for (int kk = 0; kk < 32; kk++) {
          float w = sm.g.w[kk][tx];
          float4 a = *(const float4*)&sm.g.A[kk][rg4*4];
          acc[0] = fmaf(a.x, w, acc[0]);
          acc[1] = fmaf(a.y, w, acc[1]);
          acc[2] = fmaf(a.z, w, acc[2]);
          acc[3] = fmaf(a.w, w, acc[3]);
        }
      }
      __syncthreads();
      #pragma unroll
      for (int i = 0; i < 4; i++) sm.g.gt[rg4*4 + i][tx] = acc[i];
      __syncthreads();
      float* C = ws + OFF_C;
      const float* XEb = ws + OFF_XE;
      float* XO = ws + OFF_XO;
      {
        int r = tid >> 5, jl = tid & 31;   // 16 rows x 32 h-units = 512
        float4 g4 = *(const float4*)&sm.g.gt[r][jl*4];   // i,f,g,o
        int b = r0 + r, jglob = colg*32 + jl;
        float co = C[b*HH + jglob];
        double si = 1.0/(1.0 + exp(-(double)g4.x));
        double sf = 1.0/(1.0 + exp(-(double)g4.y));
        double tg = tanh((double)g4.z);
        double so = 1.0/(1.0 + exp(-(double)g4.w));
        float c2 = (float)(sf*(double)co + si*tg);
        float h2 = (float)(so*tanh((double)c2));
        C[b*HH + jglob] = c2;
        h_nxt[b*HH + jglob] = h2;
        XO[b*HH + jglob] = h2 + XEb[b*HH + jglob];
      }
      if (bid == 0) {
        for (int p = tid; p < BB*4; p += 512) slots[p] = 0ull;
      }
    }
    __threadfence();
    gridg.sync();

    // ======== phase 4: cluster heads (f32) + fused argmax ========
    // 256 = 16 rowg x 16 colg ; tile 16 rows x 256 head-cols in 2 halves of 128, k=512 in 16 tiles of 32
    {
      int rowg = bid >> 4, colg = bid & 15;
      int r0 = rowg*16;
      int hd = colg >> 2;
      int kbase = (colg & 3)*256;
      int cp = tid & 127, rg4 = tid >> 7;
      const float* Wf = hd==0 ? P.W_fx : (hd==1 ? P.W_fy : (hd==2 ? P.W_fw : P.W_fh));
      const float* bf = hd==0 ? P.b_fx : (hd==1 ? P.b_fy : (hd==2 ? P.b_fw : P.b_fh));
      const float* XO = ws + OFF_XO;
      float* obase = out + (size_t)BB*TT*4 + (size_t)hd*BB*63*KKC;
      for (int half = 0; half < 2; half++) {
        int ko = kbase + half*128 + cp;
        float acc[4];
        float bv = bf[ko];
        #pragma unroll
        for (int i = 0; i < 4; i++) acc[i] = bv;
        for (int kt = 0; kt < 16; kt++) {
          int k0 = kt*32;
          __syncthreads();
          if (tid < 128) { // stage A: 32k x 16r
            int r = tid & 15, q = tid >> 4;
            float4 v = *(const float4*)&XO[(r0+r)*HH + k0 + q*4];
            sm.h.A[q*4+0][r] = v.x; sm.h.A[q*4+1][r] = v.y;
            sm.h.A[q*4+2][r] = v.z; sm.h.A[q*4+3][r] = v.w;
          }
          for (int p = 0; p < 2; p++) { // stage W: 32k x 128c
            int idx = tid + p*512;
            int wc = idx >> 3, kq = idx & 7;
            float4 v = *(const float4*)&Wf[(kbase + half*128 + wc)*HH + k0 + kq*4];
            sm.h.w[kq*4+0][wc] = v.x; sm.h.w[kq*4+1][wc] = v.y;
            sm.h.w[kq*4+2][wc] = v.z; sm.h.w[kq*4+3][wc] = v.w;
          }
          __syncthreads();
          #pragma unroll 4
          for (int kk = 0; kk < 32; kk++) {
            float w = sm.h.w[kk][cp];
            float4 a = *(const float4*)&sm.h.A[kk][rg4*4];
            acc[0] = fmaf(a.x, w, acc[0]);
            acc[1] = fmaf(a.y, w, acc[1]);
            acc[2] = fmaf(a.z, w, acc[2]);
            acc[3] = fmaf(a.w, w, acc[3]);
          }
        }
        #pragma unroll
        for (int i = 0; i < 4; i++) {
          int b = r0 + rg4*4 + i;
          obase[(size_t)b*63*KKC + (size_t)t*KKC + ko] = acc[i];
          unsigned long long cd = ((unsigned long long)encf(acc[i]) << 32)
                                | (unsigned long long)(0xFFFFFFFFu - (unsigned)ko);
          #pragma unroll
          for (int m = 1; m < 64; m <<= 1) {
            unsigned long long o = shfl_xor_u64(cd, m);
            cd = (o > cd) ? o : cd;
          }
          if ((tid & 63) == 0) atomicMax(&slots[b*4 + hd], cd);
        }
        __syncthreads();   // protect w/A before next half re-stage
      }
    }
    __threadfence();
    gridg.sync();
  }
}

// =================== fallback: round-13 multi-kernel path (known-good) ===================
__global__ __launch_bounds__(256) void k_init(
    const float* __restrict__ obs, const float* __restrict__ h0,
    const float* __restrict__ c0, float* __restrict__ ws,
    float* __restrict__ out)
{
  int i = blockIdx.x*256 + threadIdx.x;
  ws[OFF_HA + i] = h0[i];
  ws[OFF_C  + i] = c0[i];
  if (i < BB*4) {
    int b = i >> 2, d = i & 3;
    out[(b*TT + 0)*4 + d]  = obs[(b*TT + 0)*4 + d];
    out[(b*TT + 63)*4 + d] = obs[(b*TT + 63)*4 + d];
  }
}

__global__ __launch_bounds__(256) void k_xe(
    const float* __restrict__ obs, const float* __restrict__ cx, const float* __restrict__ cy,
    const float* __restrict__ cw, const float* __restrict__ ch, const int* maskp,
    const float* __restrict__ W_rb1, const float* __restrict__ b_rb1,
    const float* __restrict__ W_rb2, const float* __restrict__ b_rb2,
    const float* __restrict__ W_rbs, const float* __restrict__ b_rbs,
    float* __restrict__ ws, float* __restrict__ out, int t)
{
  int bid = blockIdx.x, tid = threadIdx.x;
  int rowg = bid >> 4, colg = bid & 15;
  int r0 = rowg*8, c0 = colg*32;
  __shared__ float x_sm[8][4];
  __shared__ float xr_smT[HH][8];
  __shared__ float w_sm[64][36];
  if (tid < 32) {
    int r = tid >> 2, hd = tid & 3, b = r0 + r;
    int mi = decode_mask(maskp);
    float v;
    if (t == 0 || t < mi) {
      v = obs[(b*TT + t)*4 + hd];
    } else {
      const unsigned long long* slots = (const unsigned long long*)(ws + OFF_SLOT);
      unsigned long long s = slots[b*4 + hd];
      unsigned int kidx = 0xFFFFFFFFu - (unsigned int)(s & 0xFFFFFFFFull);
      const float* cen = hd==0 ? cx : (hd==1 ? cy : (hd==2 ? cw : ch));
      v = cen[kidx & (KKC-1)];
    }
    x_sm[r][hd] = v;
    if (t >= 1 && colg == 0) out[(b*TT + t)*4 + hd] = v;
  }
  __syncthreads();
  for (int p = tid; p < 8*HH; p += 256) {
    int r = p & 7, j = p >> 3;
    float4 w = *(const float4*)&W_rb1[j*4];
    float a = b_rb1[j] + x_sm[r][0]*w.x + x_sm[r][1]*w.y + x_sm[r][2]*w.z + x_sm[r][3]*w.w;
    xr_smT[j][r] = fmaxf(a, 0.f);
  }
  int c = tid & 31, rg = tid >> 5;
  int col = c0 + c;
  float4 wsd = *(const float4*)&W_rbs[col*4];
  float acc = b_rb2[col] + b_rbs[col]
            + x_sm[rg][0]*wsd.x + x_sm[rg][1]*wsd.y
            + x_sm[rg][2]*wsd.z + x_sm[rg][3]*wsd.w;
  for (int kt = 0; kt < 8; kt++) {
    __syncthreads();
    for (int p = 0; p < 2; p++) {
      int idx = tid + p*256;
      int wc = idx >> 4, kq = idx & 15;
      float4 v = *(const float4*)&W_rb2[(c0+wc)*HH + kt*64 + kq*4];
      w_sm[kq*4+0][wc] = v.x; w_sm[kq*4+1][wc] = v.y;
      w_sm[kq*4+2][wc] = v.z; w_sm[kq*4+3][wc] = v.w;
    }
    __syncthreads();
    #pragma unroll 8
    for (int kk = 0; kk < 64; kk++)
      acc = fmaf(xr_smT[kt*64+kk][rg], w_sm[kk][c], acc);
  }
  ws[OFF_XE + (r0+rg)*HH + col] = fmaxf(acc, 0.f);
}

__global__ __launch_bounds__(256) void k_xs(
    const float* __restrict__ social, const float* __restrict__ W_emb,
    const float* __restrict__ b_emb, float* __restrict__ ws, int t)
{
  int bid = blockIdx.x, tid = threadIdx.x;
  int rowg = bid >> 4, colg = bid & 15;
  int r0 = rowg*8, c0 = colg*32;
  __shared__ float A_smT[64][12];
  __shared__ float w_sm[64][36];
  int c = tid & 31, rg = tid >> 5;
  int col = c0 + c;
  float acc = b_emb[col];
  const float* XE = ws + OFF_XE;
  for (int kt = 0; kt < 12; kt++) {
    int k0 = kt*64;
    __syncthreads();
    if (tid < 128) {
      int r = tid & 7, q = tid >> 3;
      const float* src = (kt < 8) ? &XE[(r0+r)*HH + k0 + q*4]
                                  : &social[((size_t)(r0+r)*TT + t)*SS + (k0 - HH) + q*4];
      float4 v = *(const float4*)src;
      A_smT[q*4+0][r] = v.x; A_smT[q*4+1][r] = v.y;
      A_smT[q*4+2][r] = v.z; A_smT[q*4+3][r] = v.w;
    }
    for (int p = 0; p < 2; p++) {
      int idx = tid + p*256;
      int wc = idx >> 4, kq = idx & 15;
      float4 v = *(const float4*)&W_emb[(c0+wc)*768 + k0 + kq*4];
      w_sm[kq*4+0][wc] = v.x; w_sm[kq*4+1][wc] = v.y;
      w_sm[kq*4+2][wc] = v.z; w_sm[kq*4+3][wc] = v.w;
    }
    __syncthreads();
    #pragma unroll 8
    for (int kk = 0; kk < 64; kk++)
      acc = fmaf(A_smT[kk][rg], w_sm[kk][c], acc);
  }
  ws[OFF_XS + (r0+rg)*HH + col] = fmaxf(acc, 0.f);
}

__global__ __launch_bounds__(256) void k_gates(
    const float* __restrict__ W_ih, const float* __restrict__ b_ih,
    const float* __restrict__ W_hh, const float* __restrict__ b_hh,
    float* __restrict__ ws, const float* __restrict__ h_cur,
    float* __restrict__ h_nxt)
{
  int bid = blockIdx.x, tid = threadIdx.x;
  int rowg = bid >> 5, colg = bid & 31;
  int r0 = rowg*16;
  int tx = tid & 63, ty = tid >> 6;
  __shared__ float A_smT[64][20];
  __shared__ float w_sm[64][66];
  __shared__ float gt[16][66];
  const float* XS = ws + OFF_XS;
  int wrow = (tx & 3)*HH + colg*16 + (tx >> 2);
  float bias = b_ih[wrow] + b_hh[wrow];
  float acc[4];
  #pragma unroll
  for (int i = 0; i < 4; i++) acc[i] = bias;
  for (int kt = 0; kt < 16; kt++) {
    int k0 = kt*64;
    __syncthreads();
    {
      int r = tid & 15, q = tid >> 4;
      const float* src = (kt < 8) ? &XS[(r0+r)*HH + k0 + q*4]
                                  : &h_cur[(r0+r)*HH + (k0 - HH) + q*4];
      float4 v = *(const float4*)src;
      A_smT[q*4+0][r] = v.x; A_smT[q*4+1][r] = v.y;
      A_smT[q*4+2][r] = v.z; A_smT[q*4+3][r] = v.w;
    }
    for (int p = 0; p < 4; p++) {
      int idx = tid + p*256;
      int wc = idx >> 4, kq = idx & 15;
      int wr = (wc & 3)*HH + colg*16 + (wc >> 2);
      const float* wsrc = (kt < 8) ? &W_ih[wr*HH + k0 + kq*4]
                                   : &W_hh[wr*HH + (k0 - HH) + kq*4];
      float4 v = *(const float4*)wsrc;
      w_sm[kq*4+0][wc] = v.x; w_sm[kq*4+1][wc] = v.y;
      w_sm[kq*4+2][wc] = v.z; w_sm[kq*4+3][wc] = v.w;
    }
    __syncthreads();
    #pragma unroll 4
    for (int kk = 0; kk < 64; kk++) {
      float w = w_sm[kk][tx];
      float4 a = *(const float4*)&A_smT[kk][ty*4];
      acc[0] = fmaf(a.x, w, acc[0]);
      acc[1] = fmaf(a.y, w, acc[1]);
      acc[2] = fmaf(a.z, w, acc[2]);
      acc[3] = fmaf(a.w, w, acc[3]);
    }
  }
  __syncthreads();
  #pragma unroll
  for (int i = 0; i < 4; i++) gt[ty*4 + i][tx] = acc[i];
  __syncthreads();
  float* C = ws + OFF_C;
  const float* XEb = ws + OFF_XE;
  float* XO = ws + OFF_XO;
  {
    int r = tid >> 4, jl = tid & 15;
    float4 g4 = *(const float4*)&gt[r][jl*4];
    int b = r0 + r, jglob = colg*16 + jl;
    float co = C[b*HH + jglob];
    double si = 1.0/(1.0 + exp(-(double)g4.x));
    double sf = 1.0/(1.0 + exp(-(double)g4.y));
    double tg = tanh((double)g4.z);
    double so = 1.0/(1.0 + exp(-(double)g4.w));
    float c2 = (float)(sf*(double)co + si*tg);
    float h2 = (float)(so*tanh((double)c2));
    C[b*HH + jglob] = c2;
    h_nxt[b*HH + jglob] = h2;
    XO[b*HH + jglob] = h2 + XEb[b*HH + jglob];
  }
  if (bid == 0) {
    unsigned long long* slots = (unsigned long long*)(ws + OFF_SLOT);
    for (int p = tid; p < BB*4; p += 256) slots[p] = 0ull;
  }
}

__global__ __launch_bounds__(256) void k_heads(
    const float* __restrict__ W_fx, const float* __restrict__ b_fx,
    const float* __restrict__ W_fy, const float* __restrict__ b_fy,
    const float* __restrict__ W_fw, const float* __restrict__ b_fw,
    const float* __restrict__ W_fh, const float* __restrict__ b_fh,
    float* __restrict__ ws, float* __restrict__ out, int t)
{
  int bid = blockIdx.x, tid = threadIdx.x;
  int rowg = bid >> 6, colg = bid & 63;
  int r0 = rowg*16;
  int hd = colg >> 4;
  int kbase = (colg & 15)*64;
  int tx = tid & 63, ty = tid >> 6;
  __shared__ float A_smT[64][20];
  __shared__ float w_sm[64][66];
  const float* Wf = hd==0 ? W_fx : (hd==1 ? W_fy : (hd==2 ? W_fw : W_fh));
  const float* bf = hd==0 ? b_fx : (hd==1 ? b_fy : (hd==2 ? b_fw : b_fh));
  const float* XO = ws + OFF_XO;
  int ko = kbase + tx;
  float binit = bf[ko];
  float acc[4];
  #pragma unroll
  for (int i = 0; i < 4; i++) acc[i] = binit;
  for (int kt = 0; kt < 8; kt++) {
    int k0 = kt*64;
    __syncthreads();
    {
      int r = tid & 15, q = tid >> 4;
      float4 v = *(const float4*)&XO[(r0+r)*HH + k0 + q*4];
      A_smT[q*4+0][r] = v.x; A_smT[q*4+1][r] = v.y;
      A_smT[q*4+2][r] = v.z; A_smT[q*4+3][r] = v.w;
    }
    for (int p = 0; p < 4; p++) {
      int idx = tid + p*256;
      int wc = idx >> 4, kq = idx & 15;
      float4 v = *(const float4*)&Wf[(kbase+wc)*HH + k0 + kq*4];
      w_sm[kq*4+0][wc] = v.x; w_sm[kq*4+1][wc] = v.y;
      w_sm[kq*4+2][wc] = v.z; w_sm[kq*4+3][wc] = v.w;
    }
    __syncthreads();
    #pragma unroll 4
    for (int kk = 0; kk < 64; kk++) {
      float w = w_sm[kk][tx];
      float4 a = *(const float4*)&A_smT[kk][ty*4];
      acc[0] = fmaf(a.x, w, acc[0]);
      acc[1] = fmaf(a.y, w, acc[1]);
      acc[2] = fmaf(a.z, w, acc[2]);
      acc[3] = fmaf(a.w, w, acc[3]);
    }
  }
  float* obase = out + (size_t)BB*TT*4 + (size_t)hd*BB*63*KKC;
  unsigned long long* slots = (unsigned long long*)(ws + OFF_SLOT);
  #pragma unroll
  for (int i = 0; i < 4; i++) {
    int b = r0 + ty*4 + i;
    obase[(size_t)b*63*KKC + (size_t)t*KKC + ko] = acc[i];
    unsigned long long cd = ((unsigned long long)encf(acc[i]) << 32)
                          | (unsigned long long)(0xFFFFFFFFu - (unsigned)ko);
    #pragma unroll
    for (int m = 1; m < 64; m <<= 1) {
      unsigned long long o = shfl_xor_u64(cd, m);
      cd = (o > cd) ? o : cd;
    }
    if (tx == 0) atomicMax(&slots[b*4 + hd], cd);
  }
}

extern "C" void kernel_launch(void* const* d_in, const int* in_sizes, int n_in,
                              void* d_out, int out_size, void* d_ws, size_t ws_size,
                              hipStream_t stream)
{
  KParams p;
  p.obs    = (const float*)d_in[0];
  p.social = (const float*)d_in[1];
  p.maskp  = (const int*)d_in[2];
  p.cx = (const float*)d_in[3];
  p.cy = (const float*)d_in[4];
  p.cw = (const float*)d_in[5];
  p.ch = (const float*)d_in[6];
  p.W_rb1 = (const float*)d_in[7];
  p.b_rb1 = (const float*)d_in[8];
  p.W_rb2 = (const float*)d_in[9];
  p.b_rb2 = (const float*)d_in[10];
  p.W_rbs = (const float*)d_in[11];
  p.b_rbs = (const float*)d_in[12];
  p.W_emb = (const float*)d_in[13];
  p.b_emb = (const float*)d_in[14];
  p.W_ih  = (const float*)d_in[15];
  p.b_ih  = (const float*)d_in[16];
  p.W_hh  = (const float*)d_in[17];
  p.b_hh  = (const float*)d_in[18];
  p.W_fx  = (const float*)d_in[19];
  p.b_fx  = (const float*)d_in[20];
  p.W_fy  = (const float*)d_in[21];
  p.b_fy  = (const float*)d_in[22];
  p.W_fw  = (const float*)d_in[23];
  p.b_fw  = (const float*)d_in[24];
  p.W_fh  = (const float*)d_in[25];
  p.b_fh  = (const float*)d_in[26];
  p.h0 = (const float*)d_in[27];
  p.c0 = (const float*)d_in[28];
  p.ws  = (float*)d_ws;
  p.out = (float*)d_out;

  void* args[] = { (void*)&p };
  hipError_t err = hipLaunchCooperativeKernel((const void*)k_all, dim3(256), dim3(512),
                                              args, 0, stream);
  if (err != hipSuccess) {
    (void)hipGetLastError();   // clear sticky error, use known-good multi-kernel path
    hipLaunchKernelGGL(k_init, dim3(512), dim3(256), 0, stream, p.obs, p.h0, p.c0, p.ws, p.out);
    for (int t = 0; t < 63; t++) {
      const float* h_cur = p.ws + ((t & 1) ? OFF_HB : OFF_HA);
      float*       h_nxt = p.ws + ((t & 1) ? OFF_HA : OFF_HB);
      hipLaunchKernelGGL(k_xe, dim3(512), dim3(256), 0, stream,
                         p.obs, p.cx, p.cy, p.cw, p.ch, p.maskp,
                         p.W_rb1, p.b_rb1, p.W_rb2, p.b_rb2, p.W_rbs, p.b_rbs, p.ws, p.out, t);
      hipLaunchKernelGGL(k_xs, dim3(512), dim3(256), 0, stream, p.social, p.W_emb, p.b_emb, p.ws, t);
      hipLaunchKernelGGL(k_gates, dim3(512), dim3(256), 0, stream,
                         p.W_ih, p.b_ih, p.W_hh, p.b_hh, p.ws, h_cur, h_nxt);
      hipLaunchKernelGGL(k_heads, dim3(1024), dim3(256), 0, stream,
                         p.W_fx, p.b_fx, p.W_fy, p.b_fy, p.W_fw, p.b_fw, p.W_fh, p.b_fh, p.ws, p.out, t);
    }
  }
}

// Round 16
// 8453.644 us; speedup vs baseline: 3.2060x; 3.2060x over previous
//
#include <hip/hip_runtime.h>
#include <hip/hip_bf16.h>
#include <hip/hip_fp16.h>
#include <math.h>

// Problem sizes
#define BB 256
#define TT 64
#define HH 512
#define SS 256
#define KKC 1024

// ws float offsets — 788,480 floats = 3.15 MB
#define OFF_XE 0
#define OFF_XS (OFF_XE + BB*HH)
#define OFF_HA (OFF_XS + BB*HH)
#define OFF_HB (OFF_HA + BB*HH)
#define OFF_C  (OFF_HB + BB*HH)
#define OFF_XO (OFF_C  + BB*HH)
#define OFF_SLOT (OFF_XO + BB*HH)   // 1024 u64 argmax slots

__device__ __forceinline__ unsigned encf(float f) {
  unsigned u = __float_as_uint(f);
  return (u & 0x80000000u) ? ~u : (u | 0x80000000u);
}

__device__ __forceinline__ unsigned long long shfl_xor_u64(unsigned long long v, int m) {
  unsigned lo = (unsigned)v, hi = (unsigned)(v >> 32);
  lo = __shfl_xor(lo, m, 64);
  hi = __shfl_xor(hi, m, 64);
  return ((unsigned long long)hi << 32) | lo;
}

// mask decode (robust; proven on this dataset in round 11)
__device__ __forceinline__ int decode_mask(const int* p) {
  if (p == nullptr) return 32;
  unsigned w0 = (unsigned)p[0];
  if (w0 >= 1u && w0 <= 63u) return (int)w0;
  { float f = __uint_as_float(w0);
    if (f >= 1.f && f <= 63.f && f == floorf(f)) return (int)f; }
  if (w0 == 0u) {
    double dv = __hiloint2double(p[1], 0);
    if (dv >= 1.0 && dv <= 63.0 && dv == floor(dv)) return (int)dv;
    return 32;
  }
  if (w0 <= 0xFFFFu) {
    float fb = __uint_as_float(w0 << 16);
    if (fb >= 1.f && fb <= 63.f && fb == floorf(fb)) return (int)fb;
    __half_raw hr; hr.x = (unsigned short)w0;
    float fh = __half2float(__half(hr));
    if (fh >= 1.f && fh <= 63.f && fh == floorf(fh)) return (int)fh;
  }
  return 32;
}

// ---------------- init: h,c and output edges ----------------
__global__ __launch_bounds__(256) void k_init(
    const float* __restrict__ obs, const float* __restrict__ h0,
    const float* __restrict__ c0, float* __restrict__ ws,
    float* __restrict__ out)
{
  int i = blockIdx.x*256 + threadIdx.x;   // 512 blocks -> BB*HH
  ws[OFF_HA + i] = h0[i];
  ws[OFF_C  + i] = c0[i];
  if (i < BB*4) {
    int b = i >> 2, d = i & 3;
    out[(b*TT + 0)*4 + d]  = obs[(b*TT + 0)*4 + d];
    out[(b*TT + 63)*4 + d] = obs[(b*TT + 63)*4 + d];
  }
}

// ---------------- phase 1: sample (fused) + residual block -> xe ----------------
// grid 512 = 32 rowg x 16 colg ; tile 8 rows x 32 cols, k=512 in 8 tiles of 64
__global__ __launch_bounds__(256) void k_xe(
    const float* __restrict__ obs, const float* __restrict__ cx, const float* __restrict__ cy,
    const float* __restrict__ cw, const float* __restrict__ ch, const int* maskp,
    const float* __restrict__ W_rb1, const float* __restrict__ b_rb1,
    const float* __restrict__ W_rb2, const float* __restrict__ b_rb2,
    const float* __restrict__ W_rbs, const float* __restrict__ b_rbs,
    float* __restrict__ ws, float* __restrict__ out, int t)
{
  int bid = blockIdx.x, tid = threadIdx.x;
  int rowg = bid >> 4, colg = bid & 15;
  int r0 = rowg*8, c0 = colg*32;
  __shared__ float x_sm[8][4];
  __shared__ float xr_smT[HH][8];
  __shared__ float w_sm[64][36];
  if (tid < 32) {
    int r = tid >> 2, hd = tid & 3, b = r0 + r;
    int mi = decode_mask(maskp);
    float v;
    if (t == 0 || t < mi) {
      v = obs[(b*TT + t)*4 + hd];
    } else {
      const unsigned long long* slots = (const unsigned long long*)(ws + OFF_SLOT);
      unsigned long long s = slots[b*4 + hd];
      unsigned int kidx = 0xFFFFFFFFu - (unsigned int)(s & 0xFFFFFFFFull);
      const float* cen = hd==0 ? cx : (hd==1 ? cy : (hd==2 ? cw : ch));
      v = cen[kidx & (KKC-1)];
    }
    x_sm[r][hd] = v;
    if (t >= 1 && colg == 0) out[(b*TT + t)*4 + hd] = v;
  }
  __syncthreads();
  for (int p = tid; p < 8*HH; p += 256) {
    int r = p & 7, j = p >> 3;
    float4 w = *(const float4*)&W_rb1[j*4];
    float a = b_rb1[j] + x_sm[r][0]*w.x + x_sm[r][1]*w.y + x_sm[r][2]*w.z + x_sm[r][3]*w.w;
    xr_smT[j][r] = fmaxf(a, 0.f);
  }
  int c = tid & 31, rg = tid >> 5;
  int col = c0 + c;
  float4 wsd = *(const float4*)&W_rbs[col*4];
  float acc = b_rb2[col] + b_rbs[col]
            + x_sm[rg][0]*wsd.x + x_sm[rg][1]*wsd.y
            + x_sm[rg][2]*wsd.z + x_sm[rg][3]*wsd.w;
  for (int kt = 0; kt < 8; kt++) {
    __syncthreads();
    for (int p = 0; p < 2; p++) {
      int idx = tid + p*256;
      int wc = idx >> 4, kq = idx & 15;
      float4 v = *(const float4*)&W_rb2[(c0+wc)*HH + kt*64 + kq*4];
      w_sm[kq*4+0][wc] = v.x; w_sm[kq*4+1][wc] = v.y;
      w_sm[kq*4+2][wc] = v.z; w_sm[kq*4+3][wc] = v.w;
    }
    __syncthreads();
    #pragma unroll 8
    for (int kk = 0; kk < 64; kk++)
      acc = fmaf(xr_smT[kt*64+kk][rg], w_sm[kk][c], acc);
  }
  ws[OFF_XE + (r0+rg)*HH + col] = fmaxf(acc, 0.f);
}

// ---------------- phase 2: embedding -> xs ----------------
// grid 512 = 32 rowg x 16 colg ; tile 8 x 32, k=768 in 12 tiles of 64
__global__ __launch_bounds__(256) void k_xs(
    const float* __restrict__ social, const float* __restrict__ W_emb,
    const float* __restrict__ b_emb, float* __restrict__ ws, int t)
{
  int bid = blockIdx.x, tid = threadIdx.x;
  int rowg = bid >> 4, colg = bid & 15;
  int r0 = rowg*8, c0 = colg*32;
  __shared__ float A_smT[64][12];
  __shared__ float w_sm[64][36];
  int c = tid & 31, rg = tid >> 5;
  int col = c0 + c;
  float acc = b_emb[col];
  const float* XE = ws + OFF_XE;
  for (int kt = 0; kt < 12; kt++) {
    int k0 = kt*64;
    __syncthreads();
    if (tid < 128) {
      int r = tid & 7, q = tid >> 3;
      const float* src = (kt < 8) ? &XE[(r0+r)*HH + k0 + q*4]
                                  : &social[((size_t)(r0+r)*TT + t)*SS + (k0 - HH) + q*4];
      float4 v = *(const float4*)src;
      A_smT[q*4+0][r] = v.x; A_smT[q*4+1][r] = v.y;
      A_smT[q*4+2][r] = v.z; A_smT[q*4+3][r] = v.w;
    }
    for (int p = 0; p < 2; p++) {
      int idx = tid + p*256;
      int wc = idx >> 4, kq = idx & 15;
      float4 v = *(const float4*)&W_emb[(c0+wc)*768 + k0 + kq*4];
      w_sm[kq*4+0][wc] = v.x; w_sm[kq*4+1][wc] = v.y;
      w_sm[kq*4+2][wc] = v.z; w_sm[kq*4+3][wc] = v.w;
    }
    __syncthreads();
    #pragma unroll 8
    for (int kk = 0; kk < 64; kk++)
      acc = fmaf(A_smT[kk][rg], w_sm[kk][c], acc);
  }
  ws[OFF_XS + (r0+rg)*HH + col] = fmaxf(acc, 0.f);
}

// ---------------- phase 3: LSTM gates + cell update ----------------
// grid 256 = 4 rowg x 64 colg ; tile 64 rows x 32 gate-cols (8 h-units), k=1024 in 16 tiles
// bid%8 == colg%8 -> same W slice per XCD (8 slices x 128KB = 1MB in 4MB L2)
__global__ __launch_bounds__(256) void k_gates(
    const float* __restrict__ W_ih, const float* __restrict__ b_ih,
    const float* __restrict__ W_hh, const float* __restrict__ b_hh,
    float* __restrict__ ws, const float* __restrict__ h_cur,
    float* __restrict__ h_nxt)
{
  int bid = blockIdx.x, tid = threadIdx.x;
  int rowg = bid >> 6, colg = bid & 63;
  int r0 = rowg*64;
  int c = tid & 31, rg = tid >> 5;   // col 0..31 ; row-group 0..7 (8 rows each)
  __shared__ float A_smT[64][68];    // [k][row]
  __shared__ float w_sm[64][36];     // [k][col]
  __shared__ float gt[64][36];       // [row][col] gate values
  const float* XS = ws + OFF_XS;
  int wrow = (c & 3)*HH + colg*8 + (c >> 2);   // local col c = jl*4 + g
  float bias = b_ih[wrow] + b_hh[wrow];
  float acc[8];
  #pragma unroll
  for (int i = 0; i < 8; i++) acc[i] = bias;
  for (int kt = 0; kt < 16; kt++) {
    int k0 = kt*64;
    __syncthreads();
    for (int p = 0; p < 4; p++) {   // stage A: 64k x 64r
      int idx = tid + p*256;
      int r = idx & 63, q = idx >> 6;    // q 0..15
      const float* src = (kt < 8) ? &XS[(r0+r)*HH + k0 + q*4]
                                  : &h_cur[(r0+r)*HH + (k0 - HH) + q*4];
      float4 v = *(const float4*)src;
      A_smT[q*4+0][r] = v.x; A_smT[q*4+1][r] = v.y;
      A_smT[q*4+2][r] = v.z; A_smT[q*4+3][r] = v.w;
    }
    for (int p = 0; p < 2; p++) {   // stage W: 64k x 32c
      int idx = tid + p*256;
      int wc = idx >> 4, kq = idx & 15;
      int wr = (wc & 3)*HH + colg*8 + (wc >> 2);
      const float* wsrc = (kt < 8) ? &W_ih[wr*HH + k0 + kq*4]
                                   : &W_hh[wr*HH + (k0 - HH) + kq*4];
      float4 v = *(const float4*)wsrc;
      w_sm[kq*4+0][wc] = v.x; w_sm[kq*4+1][wc] = v.y;
      w_sm[kq*4+2][wc] = v.z; w_sm[kq*4+3][wc] = v.w;
    }
    __syncthreads();
    #pragma unroll 4
    for (int kk = 0; kk < 64; kk++) {
      float w = w_sm[kk][c];
      float4 a0 = *(const float4*)&A_smT[kk][rg*8];
      float4 a1 = *(const float4*)&A_smT[kk][rg*8 + 4];
      acc[0] = fmaf(a0.x, w, acc[0]);
      acc[1] = fmaf(a0.y, w, acc[1]);
      acc[2] = fmaf(a0.z, w, acc[2]);
      acc[3] = fmaf(a0.w, w, acc[3]);
      acc[4] = fmaf(a1.x, w, acc[4]);
      acc[5] = fmaf(a1.y, w, acc[5]);
      acc[6] = fmaf(a1.z, w, acc[6]);
      acc[7] = fmaf(a1.w, w, acc[7]);
    }
  }
  __syncthreads();
  #pragma unroll
  for (int i = 0; i < 8; i++) gt[rg*8 + i][c] = acc[i];
  __syncthreads();
  float* C = ws + OFF_C;
  const float* XEb = ws + OFF_XE;
  float* XO = ws + OFF_XO;
  for (int u = 0; u < 2; u++) {   // 64 rows x 8 h-units = 512 cell updates
    int p = tid + u*256;
    int r = p >> 3, jl = p & 7;
    float4 g4 = *(const float4*)&gt[r][jl*4];   // i,f,g,o
    int b = r0 + r, jglob = colg*8 + jl;
    float co = C[b*HH + jglob];
    double si = 1.0/(1.0 + exp(-(double)g4.x));
    double sf = 1.0/(1.0 + exp(-(double)g4.y));
    double tg = tanh((double)g4.z);
    double so = 1.0/(1.0 + exp(-(double)g4.w));
    float c2 = (float)(sf*(double)co + si*tg);
    float h2 = (float)(so*tanh((double)c2));
    C[b*HH + jglob] = c2;
    h_nxt[b*HH + jglob] = h2;
    XO[b*HH + jglob] = h2 + XEb[b*HH + jglob];
  }
  if (bid == 0) {
    unsigned long long* slots = (unsigned long long*)(ws + OFF_SLOT);
    for (int p = tid; p < BB*4; p += 256) slots[p] = 0ull;
  }
}

// ---------------- phase 4: cluster heads (f32) + fused argmax ----------------
// grid 256 = 4 rowg x 64 colg ; tile 64 rows x 64 head-cols, k=512 in 8 tiles
// bid%8 == colg%8 -> per-XCD W slice 8 x 128KB = 1MB in L2
__global__ __launch_bounds__(256) void k_heads(
    const float* __restrict__ W_fx, const float* __restrict__ b_fx,
    const float* __restrict__ W_fy, const float* __restrict__ b_fy,
    const float* __restrict__ W_fw, const float* __restrict__ b_fw,
    const float* __restrict__ W_fh, const float* __restrict__ b_fh,
    float* __restrict__ ws, float* __restrict__ out, int t)
{
  int bid = blockIdx.x, tid = threadIdx.x;
  int rowg = bid >> 6, colg = bid & 63;
  int r0 = rowg*64;
  int hd = colg >> 4;
  int kbase = (colg & 15)*64;
  int tx = tid & 63, rg = tid >> 6;   // col 0..63 ; row-group 0..3 (16 rows each)
  __shared__ float A_smT[64][68];
  __shared__ float w_sm[64][68];
  const float* Wf = hd==0 ? W_fx : (hd==1 ? W_fy : (hd==2 ? W_fw : W_fh));
  const float* bf = hd==0 ? b_fx : (hd==1 ? b_fy : (hd==2 ? b_fw : b_fh));
  const float* XO = ws + OFF_XO;
  int ko = kbase + tx;
  float binit = bf[ko];
  float acc[16];
  #pragma unroll
  for (int i = 0; i < 16; i++) acc[i] = binit;
  for (int kt = 0; kt < 8; kt++) {
    int k0 = kt*64;
    __syncthreads();
    for (int p = 0; p < 4; p++) {   // stage A: 64k x 64r
      int idx = tid + p*256;
      int r = idx & 63, q = idx >> 6;
      float4 v = *(const float4*)&XO[(r0+r)*HH + k0 + q*4];
      A_smT[q*4+0][r] = v.x; A_smT[q*4+1][r] = v.y;
      A_smT[q*4+2][r] = v.z; A_smT[q*4+3][r] = v.w;
    }
    for (int p = 0; p < 4; p++) {   // stage W: 64k x 64c
      int idx = tid + p*256;
      int wc = idx >> 4, kq = idx & 15;
      float4 v = *(const float4*)&Wf[(kbase+wc)*HH + k0 + kq*4];
      w_sm[kq*4+0][wc] = v.x; w_sm[kq*4+1][wc] = v.y;
      w_sm[kq*4+2][wc] = v.z; w_sm[kq*4+3][wc] = v.w;
    }
    __syncthreads();
    #pragma unroll 2
    for (int kk = 0; kk < 64; kk++) {
      float w = w_sm[kk][tx];
      float4 a0 = *(const float4*)&A_smT[kk][rg*16];
      float4 a1 = *(const float4*)&A_smT[kk][rg*16 + 4];
      float4 a2 = *(const float4*)&A_smT[kk][rg*16 + 8];
      float4 a3 = *(const float4*)&A_smT[kk][rg*16 + 12];
      acc[0]  = fmaf(a0.x, w, acc[0]);  acc[1]  = fmaf(a0.y, w, acc[1]);
      acc[2]  = fmaf(a0.z, w, acc[2]);  acc[3]  = fmaf(a0.w, w, acc[3]);
      acc[4]  = fmaf(a1.x, w, acc[4]);  acc[5]  = fmaf(a1.y, w, acc[5]);
      acc[6]  = fmaf(a1.z, w, acc[6]);  acc[7]  = fmaf(a1.w, w, acc[7]);
      acc[8]  = fmaf(a2.x, w, acc[8]);  acc[9]  = fmaf(a2.y, w, acc[9]);
      acc[10] = fmaf(a2.z, w, acc[10]); acc[11] = fmaf(a2.w, w, acc[11]);
      acc[12] = fmaf(a3.x, w, acc[12]); acc[13] = fmaf(a3.y, w, acc[13]);
      acc[14] = fmaf(a3.z, w, acc[14]); acc[15] = fmaf(a3.w, w, acc[15]);
    }
  }
  float* obase = out + (size_t)BB*TT*4 + (size_t)hd*BB*63*KKC;
  unsigned long long* slots = (unsigned long long*)(ws + OFF_SLOT);
  #pragma unroll
  for (int i = 0; i < 16; i++) {
    int b = r0 + rg*16 + i;
    obase[(size_t)b*63*KKC + (size_t)t*KKC + ko] = acc[i];
    unsigned long long cd = ((unsigned long long)encf(acc[i]) << 32)
                          | (unsigned long long)(0xFFFFFFFFu - (unsigned)ko);
    #pragma unroll
    for (int m = 1; m < 64; m <<= 1) {
      unsigned long long o = shfl_xor_u64(cd, m);
      cd = (o > cd) ? o : cd;
    }
    if (tx == 0) atomicMax(&slots[b*4 + hd], cd);
  }
}

extern "C" void kernel_launch(void* const* d_in, const int* in_sizes, int n_in,
                              void* d_out, int out_size, void* d_ws, size_t ws_size,
                              hipStream_t stream)
{
  const float* obs    = (const float*)d_in[0];
  const float* social = (const float*)d_in[1];
  const int*   maskp  = (const int*)d_in[2];
  const float* cx = (const float*)d_in[3];
  const float* cy = (const float*)d_in[4];
  const float* cw = (const float*)d_in[5];
  const float* ch = (const float*)d_in[6];
  const float* W_rb1 = (const float*)d_in[7];
  const float* b_rb1 = (const float*)d_in[8];
  const float* W_rb2 = (const float*)d_in[9];
  const float* b_rb2 = (const float*)d_in[10];
  const float* W_rbs = (const float*)d_in[11];
  const float* b_rbs = (const float*)d_in[12];
  const float* W_emb = (const float*)d_in[13];
  const float* b_emb = (const float*)d_in[14];
  const float* W_ih  = (const float*)d_in[15];
  const float* b_ih  = (const float*)d_in[16];
  const float* W_hh  = (const float*)d_in[17];
  const float* b_hh  = (const float*)d_in[18];
  const float* W_fx  = (const float*)d_in[19];
  const float* b_fx  = (const float*)d_in[20];
  const float* W_fy  = (const float*)d_in[21];
  const float* b_fy  = (const float*)d_in[22];
  const float* W_fw  = (const float*)d_in[23];
  const float* b_fw  = (const float*)d_in[24];
  const float* W_fh  = (const float*)d_in[25];
  const float* b_fh  = (const float*)d_in[26];
  const float* h0 = (const float*)d_in[27];
  const float* c0 = (const float*)d_in[28];
  float* ws = (float*)d_ws;
  float* out = (float*)d_out;

  hipLaunchKernelGGL(k_init, dim3(512), dim3(256), 0, stream, obs, h0, c0, ws, out);

  for (int t = 0; t < 63; t++) {
    const float* h_cur = ws + ((t & 1) ? OFF_HB : OFF_HA);
    float*       h_nxt = ws + ((t & 1) ? OFF_HA : OFF_HB);
    hipLaunchKernelGGL(k_xe, dim3(512), dim3(256), 0, stream,
                       obs, cx, cy, cw, ch, maskp,
                       W_rb1, b_rb1, W_rb2, b_rb2, W_rbs, b_rbs, ws, out, t);
    hipLaunchKernelGGL(k_xs, dim3(512), dim3(256), 0, stream, social, W_emb, b_emb, ws, t);
    hipLaunchKernelGGL(k_gates, dim3(256), dim3(256), 0, stream,
                       W_ih, b_ih, W_hh, b_hh, ws, h_cur, h_nxt);
    hipLaunchKernelGGL(k_heads, dim3(256), dim3(256), 0, stream,
                       W_fx, b_fx, W_fy, b_fy, W_fw, b_fw, W_fh, b_fh, ws, out, t);
  }
}